// Round 1
// baseline (5476.737 us; speedup 1.0000x reference)
//
#include <hip/hip_runtime.h>
#include <math.h>

// B=512 batches, T=256 seq, C=384 embd, H=64 head dim. fp32 everywhere.
// Fused per-batch kernel: 1 WG = 1 batch, thread t = q-row t.
// Precision note: logits = (q.k)*sqrt(384) have std ~52 -> softmax is
// near-argmax; q/k MUST be fp32 (bf16/fp16 logit noise breaks absmax).
#define B_ 512
#define T_ 256
#define C_ 384
#define H_ 64

__global__ __launch_bounds__(256, 2)
void head_fused(const float* __restrict__ x,
                const float* __restrict__ Wq,
                const float* __restrict__ Wk,
                const float* __restrict__ Wv,
                float* __restrict__ out)
{
    // 64 KB k (full batch resident; reads are wave-uniform -> broadcast, no
    // conflicts) + 16 KB rotating v chunk = 80 KB -> exactly 2 WG/CU (160 KB).
    __shared__ __align__(16) float k_s[T_][H_];   // also reused as out-staging
    __shared__ __align__(16) float v_c[64][H_];

    const int tid = threadIdx.x;
    const int b   = blockIdx.x;
    const int t   = tid;        // q-row owned by this thread
    const int w   = tid >> 6;   // wave id 0..3

    const float* xrow = x + ((size_t)b * T_ + t) * C_;

    // ---- Phase 1: q,k,v projections for row t (192 register accumulators).
    // W addresses are wave-uniform -> compiler emits scalar s_loads (L2-hot,
    // 288 KB total). x: one float4/lane, 64B granule fully used.
    float qa[H_], ka[H_], va[H_];
    #pragma unroll
    for (int h = 0; h < H_; ++h) { qa[h] = 0.f; ka[h] = 0.f; va[h] = 0.f; }

    float4 xv = *(const float4*)(xrow);
    for (int c4 = 0; c4 < C_; c4 += 4) {
        const int cn = (c4 + 4 < C_) ? (c4 + 4) : c4;   // safe prefetch
        const float4 xnext = *(const float4*)(xrow + cn);
        const float xs4[4] = {xv.x, xv.y, xv.z, xv.w};
        #pragma unroll
        for (int cc = 0; cc < 4; ++cc) {
            const float xvv = xs4[cc];
            const float* wq = Wq + (c4 + cc) * H_;
            const float* wk = Wk + (c4 + cc) * H_;
            const float* wv = Wv + (c4 + cc) * H_;
            #pragma unroll
            for (int h = 0; h < H_; ++h) {
                qa[h] = fmaf(xvv, wq[h], qa[h]);
                ka[h] = fmaf(xvv, wk[h], ka[h]);
                va[h] = fmaf(xvv, wv[h], va[h]);
            }
        }
        xv = xnext;
    }

    // Fold SCALE = C**0.5 into q once (ref scales logits; fp-equivalent).
    constexpr float SCALE = 19.595917942265423f;  // sqrt(384)
    #pragma unroll
    for (int h = 0; h < H_; ++h) qa[h] *= SCALE;

    // ---- Phase 2a: k rows -> LDS. Staggered start spreads the 64-lane
    // same-bank-group write pattern to ~8-way.
    {
        const int st = t & 15;
        #pragma unroll
        for (int ii = 0; ii < 16; ++ii) {
            const int i = (ii + st) & 15;
            *(float4*)&k_s[t][4*i] =
                make_float4(ka[4*i], ka[4*i+1], ka[4*i+2], ka[4*i+3]);
        }
    }
    __syncthreads();

    // ---- Pass A: causal row max. Loop bound wave-uniform (wave w only needs
    // keys < 64*(w+1)). k_s reads: uniform address -> LDS broadcast.
    float m = -INFINITY;
    const int smax = (w + 1) << 6;
    #pragma unroll 1
    for (int s = 0; s < smax; ++s) {
        const float4* kp = (const float4*)k_s[s];
        float d0 = 0.f, d1 = 0.f, d2 = 0.f, d3 = 0.f;
        #pragma unroll
        for (int i = 0; i < 16; ++i) {
            const float4 kk = kp[i];
            d0 = fmaf(qa[4*i+0], kk.x, d0);
            d1 = fmaf(qa[4*i+1], kk.y, d1);
            d2 = fmaf(qa[4*i+2], kk.z, d2);
            d3 = fmaf(qa[4*i+3], kk.w, d3);
        }
        const float sc = (d0 + d1) + (d2 + d3);
        if (s <= t) m = fmaxf(m, sc);
    }

    // ---- Pass B: recompute scores, exp, accumulate PV. v rows rotate through
    // the 16 KB chunk buffer, written by the owning wave.
    float oa[H_];
    #pragma unroll
    for (int h = 0; h < H_; ++h) oa[h] = 0.f;
    float l = 0.f;

    for (int j = 0; j < 4; ++j) {
        __syncthreads();                       // protect v_c vs prev chunk
        if (w == j) {
            const int r  = t & 63;
            const int st = t & 15;
            #pragma unroll
            for (int ii = 0; ii < 16; ++ii) {
                const int i = (ii + st) & 15;
                *(float4*)&v_c[r][4*i] =
                    make_float4(va[4*i], va[4*i+1], va[4*i+2], va[4*i+3]);
            }
        }
        __syncthreads();
        if (w >= j) {                           // wave-uniform causal skip
            #pragma unroll 1
            for (int s = 0; s < 64; ++s) {
                const int gs = (j << 6) + s;
                const float4* kp = (const float4*)k_s[gs];
                float d0 = 0.f, d1 = 0.f, d2 = 0.f, d3 = 0.f;
                #pragma unroll
                for (int i = 0; i < 16; ++i) {
                    const float4 kk = kp[i];
                    d0 = fmaf(qa[4*i+0], kk.x, d0);
                    d1 = fmaf(qa[4*i+1], kk.y, d1);
                    d2 = fmaf(qa[4*i+2], kk.z, d2);
                    d3 = fmaf(qa[4*i+3], kk.w, d3);
                }
                const float sc = (d0 + d1) + (d2 + d3);
                float p = __expf(sc - m);
                p = (gs <= t) ? p : 0.f;        // mask (inf/garbage discarded)
                l += p;
                const float4* vp = (const float4*)v_c[s];
                #pragma unroll
                for (int i = 0; i < 16; ++i) {
                    const float4 vv = vp[i];
                    oa[4*i+0] = fmaf(p, vv.x, oa[4*i+0]);
                    oa[4*i+1] = fmaf(p, vv.y, oa[4*i+1]);
                    oa[4*i+2] = fmaf(p, vv.z, oa[4*i+2]);
                    oa[4*i+3] = fmaf(p, vv.w, oa[4*i+3]);
                }
            }
        }
    }

    // ---- Epilogue: normalize, stage through k_s (now dead) for coalesced
    // float4 global stores.
    __syncthreads();
    const float invl = 1.0f / l;
    {
        const int st = t & 15;
        #pragma unroll
        for (int ii = 0; ii < 16; ++ii) {
            const int i = (ii + st) & 15;
            *(float4*)&k_s[t][4*i] = make_float4(oa[4*i+0]*invl, oa[4*i+1]*invl,
                                                 oa[4*i+2]*invl, oa[4*i+3]*invl);
        }
    }
    __syncthreads();
    float4* op = (float4*)(out + (size_t)b * (T_ * H_));
    const float4* ks4 = (const float4*)&k_s[0][0];
    #pragma unroll
    for (int r = 0; r < 16; ++r) {
        const int idx = r * 256 + tid;
        op[idx] = ks4[idx];
    }
}

extern "C" void kernel_launch(void* const* d_in, const int* in_sizes, int n_in,
                              void* d_out, int out_size, void* d_ws, size_t ws_size,
                              hipStream_t stream)
{
    const float* x  = (const float*)d_in[0];
    const float* Wq = (const float*)d_in[1];
    const float* Wk = (const float*)d_in[2];
    const float* Wv = (const float*)d_in[3];
    head_fused<<<dim3(B_), dim3(T_), 0, stream>>>(x, Wq, Wk, Wv, (float*)d_out);
}

// Round 2
// 1677.195 us; speedup vs baseline: 3.2654x; 3.2654x over previous
//
#include <hip/hip_runtime.h>
#include <math.h>

// B=512 batches, T=256 seq, C=384 embd, H=64 head dim. fp32 everywhere.
// Fused per-batch kernel: 1 WG = 1 batch, thread t = q-row t.
// Precision note: logits = (q.k)*sqrt(384) have std ~52 -> softmax is
// near-argmax; q/k MUST stay fp32 (bf16 logit noise breaks absmax 5.8e-2).
//
// R2 lesson: NO dynamic indexing into register arrays (qa/ka/va/oa) — a
// single runtime index spills the whole array to scratch (R1: 27 GB HBM
// writes, 5.5 ms). LDS write bank conflicts from the plain layout are a
// one-shot ~64-cyc serialization per ds_write_b128 (48/thread) — negligible;
// LDS reads are uniform-address broadcasts (conflict-free).
#define B_ 512
#define T_ 256
#define C_ 384
#define H_ 64

__global__ __launch_bounds__(256, 2)
void head_fused(const float* __restrict__ x,
                const float* __restrict__ Wq,
                const float* __restrict__ Wk,
                const float* __restrict__ Wv,
                float* __restrict__ out)
{
    // 64 KB k (full batch resident) + 16 KB rotating v chunk = 80 KB
    // -> exactly 2 WG/CU (160 KB). k_s reused as out-staging in epilogue.
    __shared__ __align__(16) float k_s[T_][H_];
    __shared__ __align__(16) float v_c[64][H_];

    const int tid = threadIdx.x;
    const int b   = blockIdx.x;
    const int t   = tid;        // q-row owned by this thread
    const int w   = tid >> 6;   // wave id 0..3

    const float* xrow = x + ((size_t)b * T_ + t) * C_;

    // ---- Phase 1: q,k,v projections for row t (192 register accumulators).
    // W addresses are block-uniform -> scalar s_loads (L2-hot, 288 KB total).
    float qa[H_], ka[H_], va[H_];
    #pragma unroll
    for (int h = 0; h < H_; ++h) { qa[h] = 0.f; ka[h] = 0.f; va[h] = 0.f; }

    float4 xv = *(const float4*)(xrow);
    for (int c4 = 0; c4 < C_; c4 += 4) {
        const int cn = (c4 + 4 < C_) ? (c4 + 4) : c4;   // safe prefetch
        const float4 xnext = *(const float4*)(xrow + cn);
        const float xs4[4] = {xv.x, xv.y, xv.z, xv.w};
        #pragma unroll
        for (int cc = 0; cc < 4; ++cc) {
            const float xvv = xs4[cc];
            const float* wq = Wq + (c4 + cc) * H_;
            const float* wk = Wk + (c4 + cc) * H_;
            const float* wv = Wv + (c4 + cc) * H_;
            #pragma unroll
            for (int h = 0; h < H_; ++h) {
                qa[h] = fmaf(xvv, wq[h], qa[h]);
                ka[h] = fmaf(xvv, wk[h], ka[h]);
                va[h] = fmaf(xvv, wv[h], va[h]);
            }
        }
        xv = xnext;
    }

    // Fold SCALE = C**0.5 into q once (ref scales logits; fp-equivalent).
    constexpr float SCALE = 19.595917942265423f;  // sqrt(384)
    #pragma unroll
    for (int h = 0; h < H_; ++h) qa[h] *= SCALE;

    // ---- Phase 2a: k rows -> LDS (static indices only).
    #pragma unroll
    for (int i = 0; i < 16; ++i) {
        *(float4*)&k_s[t][4*i] =
            make_float4(ka[4*i], ka[4*i+1], ka[4*i+2], ka[4*i+3]);
    }
    __syncthreads();

    // ---- Pass A: causal row max. Loop bound wave-uniform (wave w only needs
    // keys < 64*(w+1)). k_s[s] reads: uniform address -> LDS broadcast.
    float m = -INFINITY;
    const int smax = (w + 1) << 6;
    #pragma unroll 1
    for (int s = 0; s < smax; ++s) {
        const float4* kp = (const float4*)k_s[s];
        float d0 = 0.f, d1 = 0.f, d2 = 0.f, d3 = 0.f;
        #pragma unroll
        for (int i = 0; i < 16; ++i) {
            const float4 kk = kp[i];
            d0 = fmaf(qa[4*i+0], kk.x, d0);
            d1 = fmaf(qa[4*i+1], kk.y, d1);
            d2 = fmaf(qa[4*i+2], kk.z, d2);
            d3 = fmaf(qa[4*i+3], kk.w, d3);
        }
        const float sc = (d0 + d1) + (d2 + d3);
        if (s <= t) m = fmaxf(m, sc);
    }

    // ---- Pass B: recompute scores, exp, accumulate PV. v rows rotate
    // through the 16 KB chunk buffer, written by the owning wave.
    float oa[H_];
    #pragma unroll
    for (int h = 0; h < H_; ++h) oa[h] = 0.f;
    float l = 0.f;

    for (int j = 0; j < 4; ++j) {
        __syncthreads();                       // protect v_c vs prev chunk
        if (w == j) {
            const int r = t & 63;
            #pragma unroll
            for (int i = 0; i < 16; ++i) {
                *(float4*)&v_c[r][4*i] =
                    make_float4(va[4*i], va[4*i+1], va[4*i+2], va[4*i+3]);
            }
        }
        __syncthreads();
        if (w >= j) {                           // wave-uniform causal skip
            #pragma unroll 1
            for (int s = 0; s < 64; ++s) {
                const int gs = (j << 6) + s;
                const float4* kp = (const float4*)k_s[gs];
                float d0 = 0.f, d1 = 0.f, d2 = 0.f, d3 = 0.f;
                #pragma unroll
                for (int i = 0; i < 16; ++i) {
                    const float4 kk = kp[i];
                    d0 = fmaf(qa[4*i+0], kk.x, d0);
                    d1 = fmaf(qa[4*i+1], kk.y, d1);
                    d2 = fmaf(qa[4*i+2], kk.z, d2);
                    d3 = fmaf(qa[4*i+3], kk.w, d3);
                }
                const float sc = (d0 + d1) + (d2 + d3);
                float p = __expf(sc - m);
                p = (gs <= t) ? p : 0.f;        // mask (garbage discarded)
                l += p;
                const float4* vp = (const float4*)v_c[s];
                #pragma unroll
                for (int i = 0; i < 16; ++i) {
                    const float4 vv = vp[i];
                    oa[4*i+0] = fmaf(p, vv.x, oa[4*i+0]);
                    oa[4*i+1] = fmaf(p, vv.y, oa[4*i+1]);
                    oa[4*i+2] = fmaf(p, vv.z, oa[4*i+2]);
                    oa[4*i+3] = fmaf(p, vv.w, oa[4*i+3]);
                }
            }
        }
    }

    // ---- Epilogue: normalize, stage through k_s (now dead) for coalesced
    // float4 global stores. Static indices only.
    __syncthreads();
    const float invl = 1.0f / l;
    #pragma unroll
    for (int i = 0; i < 16; ++i) {
        *(float4*)&k_s[t][4*i] = make_float4(oa[4*i+0]*invl, oa[4*i+1]*invl,
                                             oa[4*i+2]*invl, oa[4*i+3]*invl);
    }
    __syncthreads();
    float4* op = (float4*)(out + (size_t)b * (T_ * H_));
    const float4* ks4 = (const float4*)&k_s[0][0];
    #pragma unroll
    for (int r = 0; r < 16; ++r) {
        const int idx = r * 256 + tid;
        op[idx] = ks4[idx];
    }
}

extern "C" void kernel_launch(void* const* d_in, const int* in_sizes, int n_in,
                              void* d_out, int out_size, void* d_ws, size_t ws_size,
                              hipStream_t stream)
{
    const float* x  = (const float*)d_in[0];
    const float* Wq = (const float*)d_in[1];
    const float* Wk = (const float*)d_in[2];
    const float* Wv = (const float*)d_in[3];
    head_fused<<<dim3(B_), dim3(T_), 0, stream>>>(x, Wq, Wk, Wv, (float*)d_out);
}

// Round 3
// 1585.742 us; speedup vs baseline: 3.4537x; 1.0577x over previous
//
#include <hip/hip_runtime.h>
#include <math.h>

// B=512, T=256, C=384, H=64. fp32 everywhere (logits std ~52 because the ref
// multiplies by sqrt(C)=19.6 -> softmax near-argmax -> q/k need fp32 precision;
// bf16 logit noise ~0.2 would break absmax 5.8e-2).
//
// R3 structure (fixing R2's register-spill: VGPR capped at 128, ~160 MB scratch
// writes): projections run as THREE sequential 64-accumulator passes (Q->regs,
// K->LDS, V->LDS) so peak live regs ~155, and launch_bounds(256,1) lifts the
// VGPR cap to 512. Full k (fp32) + v (fp32) resident in LDS = 128 KB -> 1
// block/CU, 4 waves. No barriers inside the softmax passes.
#define B_ 512
#define T_ 256
#define C_ 384
#define H_ 64

// Projection pass: acc[0..63] += xrow . W[:, :] (W row-major C x H).
// Distance-2 float4 prefetch covers ~600cyc L3 latency with ~1024cyc of FMA
// per 8-column step. All indices static after unroll -> stays in VGPRs.
#define PROJ(Wm, acc)                                                        \
    do {                                                                     \
        _Pragma("unroll")                                                    \
        for (int h = 0; h < H_; ++h) (acc)[h] = 0.f;                         \
        float4 p0 = *(const float4*)(xrow + 0);                              \
        float4 p1 = *(const float4*)(xrow + 4);                              \
        for (int c8 = 0; c8 < C_; c8 += 8) {                                 \
            const int cn = (c8 + 8 < C_) ? (c8 + 8) : c8;                    \
            float4 n0 = *(const float4*)(xrow + cn);                         \
            float4 n1 = *(const float4*)(xrow + cn + 4);                     \
            const float xs[8] = {p0.x, p0.y, p0.z, p0.w,                     \
                                 p1.x, p1.y, p1.z, p1.w};                    \
            _Pragma("unroll")                                                \
            for (int cc = 0; cc < 8; ++cc) {                                 \
                const float xv = xs[cc];                                     \
                const float* wr = (Wm) + (c8 + cc) * H_;                     \
                _Pragma("unroll")                                            \
                for (int h = 0; h < H_; ++h)                                 \
                    (acc)[h] = fmaf(xv, wr[h], (acc)[h]);                    \
            }                                                                \
            p0 = n0; p1 = n1;                                                \
        }                                                                    \
    } while (0)

__global__ __launch_bounds__(256, 1)
void head_fused(const float* __restrict__ x,
                const float* __restrict__ Wq,
                const float* __restrict__ Wk,
                const float* __restrict__ Wv,
                float* __restrict__ out)
{
    __shared__ __align__(16) float k_s[T_][H_];   // 64 KB; reused for out-staging
    __shared__ __align__(16) float v_s[T_][H_];   // 64 KB

    const int tid = threadIdx.x;
    const int b   = blockIdx.x;
    const int t   = tid;        // q-row owned by this thread
    const int w   = tid >> 6;   // wave id 0..3

    const float* xrow = x + ((size_t)b * T_ + t) * C_;

    // ---- Projections: Q (persists in regs), then K -> LDS, then V -> LDS.
    float qa[H_];
    PROJ(Wq, qa);
    constexpr float SCALE = 19.595917942265423f;  // sqrt(384), folded into q
    #pragma unroll
    for (int h = 0; h < H_; ++h) qa[h] *= SCALE;

    {
        float ka[H_];
        PROJ(Wk, ka);
        #pragma unroll
        for (int i = 0; i < 16; ++i)
            *(float4*)&k_s[t][4*i] =
                make_float4(ka[4*i], ka[4*i+1], ka[4*i+2], ka[4*i+3]);
    }
    {
        float va[H_];
        PROJ(Wv, va);
        #pragma unroll
        for (int i = 0; i < 16; ++i)
            *(float4*)&v_s[t][4*i] =
                make_float4(va[4*i], va[4*i+1], va[4*i+2], va[4*i+3]);
    }
    __syncthreads();

    // ---- Pass A: causal row max. Wave-uniform bound: wave w needs s < 64(w+1).
    // k_s[s] reads are wave-uniform -> LDS broadcast (conflict-free).
    float m = -INFINITY;
    const int smax = (w + 1) << 6;
    #pragma unroll 2
    for (int s = 0; s < smax; ++s) {
        const float4* kp = (const float4*)k_s[s];
        float d0 = 0.f, d1 = 0.f, d2 = 0.f, d3 = 0.f;
        #pragma unroll
        for (int i = 0; i < 16; ++i) {
            const float4 kk = kp[i];
            d0 = fmaf(qa[4*i+0], kk.x, d0);
            d1 = fmaf(qa[4*i+1], kk.y, d1);
            d2 = fmaf(qa[4*i+2], kk.z, d2);
            d3 = fmaf(qa[4*i+3], kk.w, d3);
        }
        const float sc = (d0 + d1) + (d2 + d3);
        if (s <= t) m = fmaxf(m, sc);
    }

    // ---- Pass B: recompute logits, exp, accumulate PV. No barriers (v_s fully
    // resident). Masked lanes (s>t) force p=0 before any FMA sees it.
    float oa[H_];
    #pragma unroll
    for (int h = 0; h < H_; ++h) oa[h] = 0.f;
    float l = 0.f;

    #pragma unroll 1
    for (int s = 0; s < smax; ++s) {
        const float4* kp = (const float4*)k_s[s];
        float d0 = 0.f, d1 = 0.f, d2 = 0.f, d3 = 0.f;
        #pragma unroll
        for (int i = 0; i < 16; ++i) {
            const float4 kk = kp[i];
            d0 = fmaf(qa[4*i+0], kk.x, d0);
            d1 = fmaf(qa[4*i+1], kk.y, d1);
            d2 = fmaf(qa[4*i+2], kk.z, d2);
            d3 = fmaf(qa[4*i+3], kk.w, d3);
        }
        const float sc = (d0 + d1) + (d2 + d3);
        float p = __expf(sc - m);
        p = (s <= t) ? p : 0.f;
        l += p;
        const float4* vp = (const float4*)v_s[s];
        #pragma unroll
        for (int i = 0; i < 16; ++i) {
            const float4 vv = vp[i];
            oa[4*i+0] = fmaf(p, vv.x, oa[4*i+0]);
            oa[4*i+1] = fmaf(p, vv.y, oa[4*i+1]);
            oa[4*i+2] = fmaf(p, vv.z, oa[4*i+2]);
            oa[4*i+3] = fmaf(p, vv.w, oa[4*i+3]);
        }
    }

    // ---- Epilogue: normalize, stage through k_s (dead after all waves pass
    // the barrier) for coalesced float4 stores.
    __syncthreads();
    const float invl = 1.0f / l;
    #pragma unroll
    for (int i = 0; i < 16; ++i)
        *(float4*)&k_s[t][4*i] = make_float4(oa[4*i+0]*invl, oa[4*i+1]*invl,
                                             oa[4*i+2]*invl, oa[4*i+3]*invl);
    __syncthreads();
    float4* op = (float4*)(out + (size_t)b * (T_ * H_));
    const float4* ks4 = (const float4*)&k_s[0][0];
    #pragma unroll
    for (int r = 0; r < 16; ++r) {
        const int idx = r * 256 + tid;
        op[idx] = ks4[idx];
    }
}

extern "C" void kernel_launch(void* const* d_in, const int* in_sizes, int n_in,
                              void* d_out, int out_size, void* d_ws, size_t ws_size,
                              hipStream_t stream)
{
    const float* x  = (const float*)d_in[0];
    const float* Wq = (const float*)d_in[1];
    const float* Wk = (const float*)d_in[2];
    const float* Wv = (const float*)d_in[3];
    head_fused<<<dim3(B_), dim3(T_), 0, stream>>>(x, Wq, Wk, Wv, (float*)d_out);
}

// Round 4
// 384.046 us; speedup vs baseline: 14.2606x; 4.1290x over previous
//
#include <hip/hip_runtime.h>
#include <math.h>

// B=512, T=256, C=384, H=64. One block = one batch, 256 thr = 4 waves.
// All GEMMs on MFMA bf16 16x16x32 with hi/lo split (3-term) for x,W,q,k
// (logits sigma~52 -> need ~fp32; split gives ~2^-16 rel). P,V single bf16.
// R3 lesson: 1 wave/SIMD fp32-VALU design is latency-bound (VALUBusy 20%);
// matrix pipe is the structural fix.
#define B_ 512
#define T_ 256
#define C_ 384
#define H_ 64

typedef __attribute__((ext_vector_type(8))) short bf16x8;
typedef __attribute__((ext_vector_type(4))) float f32x4;

#define MFMA16(a, b, c) __builtin_amdgcn_mfma_f32_16x16x32_bf16((a), (b), (c), 0, 0, 0)

// ---- LDS map (bytes), total 148480 <= 163840. Strides padded (+8 elem) so
// row-stride in dwords has gcd(.,32)<=4 -> <=2-way conflicts; all frag reads
// 16B-aligned.
#define SM_KHI   0u        // khi[256][72] bf16 (row key, col h)
#define SM_KLO   36864u    // klo[256][72]
#define SM_VT    73728u    // vT[64][264] bf16 (row h, col key)
#define SM_WQH   73728u    // W-chunk staging WT[64][40], aliased over VT
#define SM_WQL   78848u
#define SM_WKH   83968u
#define SM_WKL   89088u
#define SM_WVH   94208u
#define SM_WVL   99328u
#define SM_XREG  107520u   // x-chunk staging; later q-slots; later P-slots
#define SM_XH    107520u   // xh[256][40] bf16
#define SM_XL    128000u   // xl[256][40]
#define SM_QS(s) (SM_XREG + (unsigned)(s)*18432u)  // qh[64][72] + ql[64][72]
#define SM_PS(w) (SM_XREG + (unsigned)(w)*9216u)   // p[64][72] per wave
#define SM_BYTES 148480u

static __device__ __forceinline__ unsigned short bhi(float x) {
    return (unsigned short)(__float_as_uint(x) >> 16);            // truncate
}
static __device__ __forceinline__ unsigned short blo(float x) {
    float h = __uint_as_float((__float_as_uint(x) >> 16) << 16);
    return (unsigned short)(__float_as_uint(x - h) >> 16);        // residual
}
static __device__ __forceinline__ unsigned short brne(float x) { // round-NE
    unsigned u = __float_as_uint(x);
    return (unsigned short)((u + 0x7FFFu + ((u >> 16) & 1u)) >> 16);
}
static __device__ __forceinline__ unsigned pk_hi(float a, float b) {
    return (unsigned)bhi(a) | ((unsigned)bhi(b) << 16);
}
static __device__ __forceinline__ unsigned pk_lo(float a, float b) {
    return (unsigned)blo(a) | ((unsigned)blo(b) << 16);
}

__global__ __launch_bounds__(256, 1)
void head_mfma(const float* __restrict__ x,
               const float* __restrict__ Wq,
               const float* __restrict__ Wk,
               const float* __restrict__ Wv,
               float* __restrict__ out)
{
    __shared__ __align__(16) unsigned char sm[SM_BYTES];

    const int tid  = threadIdx.x;
    const int b    = blockIdx.x;
    const int w    = tid >> 6;        // wave 0..3, owns q-rows [64w,64w+64)
    const int lane = tid & 63;
    const int l15  = lane & 15;
    const int quad = lane >> 4;
    const int w64  = w * 64;

    // ================= Phase 1: q,k,v projections via MFMA =================
    f32x4 qac[4][4], kac[4][4], vac[4][4];
    #pragma unroll
    for (int mt = 0; mt < 4; ++mt)
        #pragma unroll
        for (int nt = 0; nt < 4; ++nt) {
            f32x4 z = {0.f, 0.f, 0.f, 0.f};
            qac[mt][nt] = z; kac[mt][nt] = z; vac[mt][nt] = z;
        }

    const float* xrow = x + ((size_t)b * T_ + tid) * C_;   // thread t stages row t
    const int hW  = tid >> 2;            // W staging: thread -> (h, c-group)
    const int cgW = (tid & 3) * 8;

    float4 xb[8];
    float  wbq[8], wbk[8], wbv[8];
    {   // prefetch chunk 0
        const float4* xp = (const float4*)(xrow);
        #pragma unroll
        for (int j = 0; j < 8; ++j) xb[j] = xp[j];
        const float* q0 = Wq + (size_t)cgW * H_ + hW;
        const float* k0 = Wk + (size_t)cgW * H_ + hW;
        const float* v0 = Wv + (size_t)cgW * H_ + hW;
        #pragma unroll
        for (int j = 0; j < 8; ++j) { wbq[j] = q0[j*H_]; wbk[j] = k0[j*H_]; wbv[j] = v0[j*H_]; }
    }

    #pragma unroll 1
    for (int cc = 0; cc < 12; ++cc) {
        // ---- stage x chunk: xh/xl[tid][0..31], stride 40 elem (80 B)
        #pragma unroll
        for (int j = 0; j < 8; ++j) {
            uint2 hh, ll;
            hh.x = pk_hi(xb[j].x, xb[j].y); hh.y = pk_hi(xb[j].z, xb[j].w);
            ll.x = pk_lo(xb[j].x, xb[j].y); ll.y = pk_lo(xb[j].z, xb[j].w);
            *(uint2*)&sm[SM_XH + (unsigned)(tid*80 + j*8)] = hh;
            *(uint2*)&sm[SM_XL + (unsigned)(tid*80 + j*8)] = ll;
        }
        // ---- stage W chunks transposed: WT[h][c'], stride 40 elem
        {
            const unsigned wo = (unsigned)(hW*80 + (tid&3)*16);
            uint4 t;
            t.x=pk_hi(wbq[0],wbq[1]); t.y=pk_hi(wbq[2],wbq[3]); t.z=pk_hi(wbq[4],wbq[5]); t.w=pk_hi(wbq[6],wbq[7]);
            *(uint4*)&sm[SM_WQH + wo] = t;
            t.x=pk_lo(wbq[0],wbq[1]); t.y=pk_lo(wbq[2],wbq[3]); t.z=pk_lo(wbq[4],wbq[5]); t.w=pk_lo(wbq[6],wbq[7]);
            *(uint4*)&sm[SM_WQL + wo] = t;
            t.x=pk_hi(wbk[0],wbk[1]); t.y=pk_hi(wbk[2],wbk[3]); t.z=pk_hi(wbk[4],wbk[5]); t.w=pk_hi(wbk[6],wbk[7]);
            *(uint4*)&sm[SM_WKH + wo] = t;
            t.x=pk_lo(wbk[0],wbk[1]); t.y=pk_lo(wbk[2],wbk[3]); t.z=pk_lo(wbk[4],wbk[5]); t.w=pk_lo(wbk[6],wbk[7]);
            *(uint4*)&sm[SM_WKL + wo] = t;
            t.x=pk_hi(wbv[0],wbv[1]); t.y=pk_hi(wbv[2],wbv[3]); t.z=pk_hi(wbv[4],wbv[5]); t.w=pk_hi(wbv[6],wbv[7]);
            *(uint4*)&sm[SM_WVH + wo] = t;
            t.x=pk_lo(wbv[0],wbv[1]); t.y=pk_lo(wbv[2],wbv[3]); t.z=pk_lo(wbv[4],wbv[5]); t.w=pk_lo(wbv[6],wbv[7]);
            *(uint4*)&sm[SM_WVL + wo] = t;
        }
        __syncthreads();

        // ---- prefetch next chunk (overlaps MFMA below)
        if (cc < 11) {
            const float4* xp = (const float4*)(xrow + (cc + 1) * 32);
            #pragma unroll
            for (int j = 0; j < 8; ++j) xb[j] = xp[j];
            const size_t c0 = (size_t)((cc + 1) * 32 + cgW) * H_ + hW;
            #pragma unroll
            for (int j = 0; j < 8; ++j) {
                wbq[j] = Wq[c0 + (size_t)j*H_];
                wbk[j] = Wk[c0 + (size_t)j*H_];
                wbv[j] = Wv[c0 + (size_t)j*H_];
            }
        }

        // ---- A fragments (wave's 64 rows), hi & lo
        bf16x8 ah[4], al[4];
        #pragma unroll
        for (int mt = 0; mt < 4; ++mt) {
            const unsigned ro = (unsigned)((w64 + mt*16 + l15)*80 + quad*16);
            ah[mt] = *(const bf16x8*)&sm[SM_XH + ro];
            al[mt] = *(const bf16x8*)&sm[SM_XL + ro];
        }
        // ---- 3-term MFMA per matrix
#define PROJ_MAT(WTH, WTL, ACC)                                               \
        {                                                                     \
            bf16x8 bh[4], bl[4];                                              \
            _Pragma("unroll")                                                 \
            for (int nt = 0; nt < 4; ++nt) {                                  \
                const unsigned bo = (unsigned)((nt*16 + l15)*80 + quad*16);   \
                bh[nt] = *(const bf16x8*)&sm[(WTH) + bo];                     \
                bl[nt] = *(const bf16x8*)&sm[(WTL) + bo];                     \
            }                                                                 \
            _Pragma("unroll")                                                 \
            for (int mt = 0; mt < 4; ++mt)                                    \
                _Pragma("unroll")                                             \
                for (int nt = 0; nt < 4; ++nt) {                              \
                    f32x4 a = ACC[mt][nt];                                    \
                    a = MFMA16(al[mt], bh[nt], a);                            \
                    a = MFMA16(ah[mt], bl[nt], a);                            \
                    a = MFMA16(ah[mt], bh[nt], a);                            \
                    ACC[mt][nt] = a;                                          \
                }                                                             \
        }
        PROJ_MAT(SM_WQH, SM_WQL, qac)
        PROJ_MAT(SM_WKH, SM_WKL, kac)
        PROJ_MAT(SM_WVH, SM_WVL, vac)
        __syncthreads();   // staging consumed; next chunk may overwrite
    }

    // ====== Phase 1 epilogue: k -> khi/klo, v -> vT, q -> A-frags ==========
    constexpr float SCALE = 19.595917942265423f;   // sqrt(384) folded into q
    // C/D layout: row = quad*4 + reg (within 16-tile), col = l15.
    #pragma unroll
    for (int mt = 0; mt < 4; ++mt)
        #pragma unroll
        for (int nt = 0; nt < 4; ++nt) {
            const f32x4 kv = kac[mt][nt];
            const f32x4 vv = vac[mt][nt];
            #pragma unroll
            for (int r = 0; r < 4; ++r) {
                const int row = w64 + mt*16 + quad*4 + r;
                const int h   = nt*16 + l15;
                *(unsigned short*)&sm[SM_KHI + (unsigned)(row*144 + h*2)] = bhi(kv[r]);
                *(unsigned short*)&sm[SM_KLO + (unsigned)(row*144 + h*2)] = blo(kv[r]);
                *(unsigned short*)&sm[SM_VT  + (unsigned)(h*528 + row*2)] = brne(vv[r]);
            }
        }

    bf16x8 qAh[4][2], qAl[4][2];
    const int slot = w & 1;
    // two shifts through 2 q-transpose slots (aliased over x staging region)
#define Q_XPOSE()                                                             \
    {                                                                         \
        const unsigned qb = SM_QS(slot);                                      \
        _Pragma("unroll")                                                     \
        for (int mt = 0; mt < 4; ++mt)                                        \
            _Pragma("unroll")                                                 \
            for (int nt = 0; nt < 4; ++nt) {                                  \
                const f32x4 qv = qac[mt][nt];                                 \
                _Pragma("unroll")                                             \
                for (int r = 0; r < 4; ++r) {                                 \
                    const float qs = qv[r] * SCALE;                           \
                    const int rl = mt*16 + quad*4 + r;                        \
                    const int h  = nt*16 + l15;                               \
                    *(unsigned short*)&sm[qb +         (unsigned)(rl*144 + h*2)] = bhi(qs); \
                    *(unsigned short*)&sm[qb + 9216u + (unsigned)(rl*144 + h*2)] = blo(qs); \
                }                                                             \
            }                                                                 \
        _Pragma("unroll")                                                     \
        for (int mt = 0; mt < 4; ++mt)                                        \
            _Pragma("unroll")                                                 \
            for (int ks = 0; ks < 2; ++ks) {                                  \
                const unsigned qo = (unsigned)((mt*16 + l15)*144 + ks*64 + quad*16); \
                qAh[mt][ks] = *(const bf16x8*)&sm[qb + qo];                   \
                qAl[mt][ks] = *(const bf16x8*)&sm[qb + 9216u + qo];           \
            }                                                                 \
    }
    if (w < 2) Q_XPOSE();
    __syncthreads();            // khi/klo/vT visible; slots free for waves 2,3
    if (w >= 2) Q_XPOSE();
    __syncthreads();            // q-slot area free -> becomes P slots

    // ================= Phase 2: flash attention, wave-local ================
    f32x4 oac[4][4];
    float m_[4][4], l_[4][4];
    #pragma unroll
    for (int mt = 0; mt < 4; ++mt) {
        #pragma unroll
        for (int nt = 0; nt < 4; ++nt) { f32x4 z = {0.f,0.f,0.f,0.f}; oac[mt][nt] = z; }
        #pragma unroll
        for (int r = 0; r < 4; ++r) { m_[mt][r] = -1e30f; l_[mt][r] = 0.f; }
    }
    const unsigned pb = SM_PS(w);

    #pragma unroll 1
    for (int kb = 0; kb <= w; ++kb) {
        // ---- S = q k^T (3-term split), 64 rows x 64 keys
        bf16x8 kbh[4][2], kbl[4][2];
        #pragma unroll
        for (int nt = 0; nt < 4; ++nt)
            #pragma unroll
            for (int ks = 0; ks < 2; ++ks) {
                const unsigned ko = (unsigned)((kb*64 + nt*16 + l15)*144 + ks*64 + quad*16);
                kbh[nt][ks] = *(const bf16x8*)&sm[SM_KHI + ko];
                kbl[nt][ks] = *(const bf16x8*)&sm[SM_KLO + ko];
            }
        f32x4 sac[4][4];
        #pragma unroll
        for (int mt = 0; mt < 4; ++mt)
            #pragma unroll
            for (int nt = 0; nt < 4; ++nt) {
                f32x4 a = {0.f,0.f,0.f,0.f};
                #pragma unroll
                for (int ks = 0; ks < 2; ++ks) {
                    a = MFMA16(qAl[mt][ks], kbh[nt][ks], a);
                    a = MFMA16(qAh[mt][ks], kbl[nt][ks], a);
                    a = MFMA16(qAh[mt][ks], kbh[nt][ks], a);
                }
                sac[mt][nt] = a;
            }
        // ---- causal mask on diagonal block
        if (kb == w) {
            #pragma unroll
            for (int mt = 0; mt < 4; ++mt)
                #pragma unroll
                for (int nt = 0; nt < 4; ++nt)
                    #pragma unroll
                    for (int r = 0; r < 4; ++r) {
                        const int rl = mt*16 + quad*4 + r;
                        const int kl = nt*16 + l15;
                        if (kl > rl) sac[mt][nt][r] = -1e30f;
                    }
        }
        // ---- online softmax (row stats live per (quad,reg); cols in lanes)
        #pragma unroll
        for (int mt = 0; mt < 4; ++mt) {
            f32x4 mx = sac[mt][0];
            #pragma unroll
            for (int nt = 1; nt < 4; ++nt) {
                #pragma unroll
                for (int r = 0; r < 4; ++r) mx[r] = fmaxf(mx[r], sac[mt][nt][r]);
            }
            #pragma unroll
            for (int r = 0; r < 4; ++r) {
                float v = mx[r];
                v = fmaxf(v, __shfl_xor(v, 1)); v = fmaxf(v, __shfl_xor(v, 2));
                v = fmaxf(v, __shfl_xor(v, 4)); v = fmaxf(v, __shfl_xor(v, 8));
                const float mnew  = fmaxf(m_[mt][r], v);
                const float alpha = __expf(m_[mt][r] - mnew);
                m_[mt][r] = mnew;
                float rs = 0.f;
                #pragma unroll
                for (int nt = 0; nt < 4; ++nt) {
                    const float p = __expf(sac[mt][nt][r] - mnew);
                    sac[mt][nt][r] = p;
                    rs += p;
                }
                rs += __shfl_xor(rs, 1); rs += __shfl_xor(rs, 2);
                rs += __shfl_xor(rs, 4); rs += __shfl_xor(rs, 8);
                l_[mt][r] = l_[mt][r] * alpha + rs;
                #pragma unroll
                for (int nt = 0; nt < 4; ++nt) oac[mt][nt][r] *= alpha;
                // P -> bf16 in wave's P slot [64 rows][72 keys]
                const int rl = mt*16 + quad*4 + r;
                #pragma unroll
                for (int nt = 0; nt < 4; ++nt)
                    *(unsigned short*)&sm[pb + (unsigned)(rl*144 + (nt*16 + l15)*2)] =
                        brne(sac[mt][nt][r]);
            }
        }
        // ---- O += P V  (P via A-frags from slot; V from vT)
        bf16x8 pA[4][2], vB[4][2];
        #pragma unroll
        for (int mt = 0; mt < 4; ++mt)
            #pragma unroll
            for (int ks = 0; ks < 2; ++ks)
                pA[mt][ks] = *(const bf16x8*)&sm[pb + (unsigned)((mt*16 + l15)*144 + ks*64 + quad*16)];
        #pragma unroll
        for (int nt = 0; nt < 4; ++nt)
            #pragma unroll
            for (int ks = 0; ks < 2; ++ks)
                vB[nt][ks] = *(const bf16x8*)&sm[SM_VT + (unsigned)((nt*16 + l15)*528 + kb*128 + ks*64 + quad*16)];
        #pragma unroll
        for (int mt = 0; mt < 4; ++mt)
            #pragma unroll
            for (int nt = 0; nt < 4; ++nt) {
                f32x4 a = oac[mt][nt];
                a = MFMA16(pA[mt][0], vB[nt][0], a);
                a = MFMA16(pA[mt][1], vB[nt][1], a);
                oac[mt][nt] = a;
            }
    }

    // ================= Epilogue: normalize + store =========================
    float inv[4][4];
    #pragma unroll
    for (int mt = 0; mt < 4; ++mt)
        #pragma unroll
        for (int r = 0; r < 4; ++r) inv[mt][r] = 1.0f / l_[mt][r];
    float* ob = out + (size_t)b * (T_ * H_);
    #pragma unroll
    for (int mt = 0; mt < 4; ++mt)
        #pragma unroll
        for (int nt = 0; nt < 4; ++nt)
            #pragma unroll
            for (int r = 0; r < 4; ++r) {
                const int row = w64 + mt*16 + quad*4 + r;
                const int h   = nt*16 + l15;
                ob[row*64 + h] = oac[mt][nt][r] * inv[mt][r];
            }
}

extern "C" void kernel_launch(void* const* d_in, const int* in_sizes, int n_in,
                              void* d_out, int out_size, void* d_ws, size_t ws_size,
                              hipStream_t stream)
{
    const float* x  = (const float*)d_in[0];
    const float* Wq = (const float*)d_in[1];
    const float* Wk = (const float*)d_in[2];
    const float* Wv = (const float*)d_in[3];
    head_mfma<<<dim3(B_), dim3(T_), 0, stream>>>(x, Wq, Wk, Wv, (float*)d_out);
}